// Round 2
// baseline (314.518 us; speedup 1.0000x reference)
//
#include <hip/hip_runtime.h>
#include <hip/hip_bf16.h>

// Fully-fused LeNet forward. 8 images per 256-thread block. No d_ws usage.
// LDS budget: scratch 39168 + p2L 14336 + h1s 4224 + h2s 2176 + conv w 4992
//           = 64896 B <= 65536.
__global__ __launch_bounds__(256) void lenet_fused(
    const float* __restrict__ X,
    const float* __restrict__ W1, const float* __restrict__ B1,
    const float* __restrict__ W2, const float* __restrict__ B2,
    const float* __restrict__ FW, const float* __restrict__ FB,
    const float* __restrict__ F2W, const float* __restrict__ F2B,
    const float* __restrict__ F3W, const float* __restrict__ F3B,
    float* __restrict__ OUT) {
  __shared__ __align__(16) float scratch[9792];  // phase-aliased (39168 B)
  __shared__ float p2L[8][448];  // pool2 flat [img][400 used; 400..447 zeroed]
  __shared__ float h1s[8][132];  // fc1 out
  __shared__ float h2s[8][68];   // fc2 out
  __shared__ float wc1t[9][8];
  __shared__ float bc1[8];
  __shared__ float wc2t[8][9][16];
  __shared__ float bc2[16];

  const int tid = threadIdx.x;
  const int m8 = blockIdx.x * 8;

  // ---- conv weights to LDS + zero p2L pad columns ----
  if (tid < 72) wc1t[tid % 9][tid / 9] = W1[tid];
  else if (tid < 80) bc1[tid - 72] = B1[tid - 72];
  else if (tid < 96) bc2[tid - 80] = B2[tid - 80];
  for (int i = tid; i < 1152; i += 256) {
    int oc = i / 72, r = i % 72;
    wc2t[r / 9][r % 9][oc] = W2[i];
  }
  for (int i = tid; i < 384; i += 256)           // 8 imgs x 48 pad cols
    p2L[i / 48][400 + (i % 48)] = 0.f;

  float* xs = scratch;          // [4][784]
  float* p1 = scratch + 3136;   // [4][8][13][16]

  // ---- conv stages: two passes of 4 images ----
  for (int p = 0; p < 2; ++p) {
    for (int i = tid; i < 784; i += 256) {       // 4 imgs x 196 float4
      int m = i / 196, f = i % 196;
      ((float4*)(xs + m * 784))[f] =
          ((const float4*)(X + (size_t)(m8 + 4 * p + m) * 784))[f];
    }
    __syncthreads();  // xs ready (also: weights on p==0; p1 free on p==1)

    // conv1 + relu + pool -> p1[m][ch][13][13]
    for (int t = tid; t < 416; t += 256) {
      int ch = t & 7;
      int rm = t >> 3;                 // 0..51
      int m = rm / 13, r = rm % 13;
      float wk[9];
#pragma unroll
      for (int k = 0; k < 9; k++) wk[k] = wc1t[k][ch];
      float b = bc1[ch];
      const float* Xb = xs + m * 784 + 2 * r * 28;
      float a[4][4];
#pragma unroll
      for (int row = 0; row < 4; row++) {
        a[row][0] = Xb[row * 28 + 0];
        a[row][1] = Xb[row * 28 + 1];
        a[row][2] = Xb[row * 28 + 2];
        a[row][3] = Xb[row * 28 + 3];
      }
#pragma unroll
      for (int c = 0; c < 13; c++) {
        if (c) {
#pragma unroll
          for (int row = 0; row < 4; row++) {
            a[row][0] = a[row][2];
            a[row][1] = a[row][3];
            a[row][2] = Xb[row * 28 + 2 * c + 2];
            a[row][3] = Xb[row * 28 + 2 * c + 3];
          }
        }
        float s0 = 0.f, s1 = 0.f, s2 = 0.f, s3 = 0.f;
#pragma unroll
        for (int u = 0; u < 3; u++)
#pragma unroll
          for (int v = 0; v < 3; v++) {
            float wv = wk[u * 3 + v];
            s0 += wv * a[u][v];
            s1 += wv * a[u][v + 1];
            s2 += wv * a[u + 1][v];
            s3 += wv * a[u + 1][v + 1];
          }
        float mx = fmaxf(fmaxf(s0, s1), fmaxf(s2, s3));
        p1[((m * 8 + ch) * 13 + r) * 16 + c] = fmaxf(mx + b, 0.f);
      }
    }
    __syncthreads();  // p1 ready; xs reads done

    // conv2 + relu + pool -> p2L[4p+m][oc*25 + r*5 + c]
    for (int t = tid; t < 320; t += 256) {
      int oc = t & 15;
      int rm = t >> 4;                 // 0..19
      int m = rm / 5, r = rm % 5;
      float acc0[10], acc1[10];
#pragma unroll
      for (int j = 0; j < 10; j++) { acc0[j] = 0.f; acc1[j] = 0.f; }
      for (int ic = 0; ic < 8; ic++) {
        float wk[9];
#pragma unroll
        for (int k = 0; k < 9; k++) wk[k] = wc2t[ic][k][oc];
        float q[4][12];
#pragma unroll
        for (int row = 0; row < 4; row++) {
          const float4* src =
              (const float4*)(p1 + ((m * 8 + ic) * 13 + 2 * r + row) * 16);
          float4 t0 = src[0], t1 = src[1], t2 = src[2];
          q[row][0] = t0.x; q[row][1] = t0.y; q[row][2] = t0.z; q[row][3] = t0.w;
          q[row][4] = t1.x; q[row][5] = t1.y; q[row][6] = t1.z; q[row][7] = t1.w;
          q[row][8] = t2.x; q[row][9] = t2.y; q[row][10] = t2.z; q[row][11] = t2.w;
        }
#pragma unroll
        for (int j = 0; j < 10; j++) {
#pragma unroll
          for (int u = 0; u < 3; u++)
#pragma unroll
            for (int v = 0; v < 3; v++) {
              float wv = wk[u * 3 + v];
              acc0[j] += wv * q[u][j + v];
              acc1[j] += wv * q[u + 1][j + v];
            }
        }
      }
      float b = bc2[oc];
#pragma unroll
      for (int c = 0; c < 5; c++) {
        float mx = fmaxf(fmaxf(acc0[2 * c], acc0[2 * c + 1]),
                         fmaxf(acc1[2 * c], acc1[2 * c + 1]));
        p2L[4 * p + m][oc * 25 + r * 5 + c] = fmaxf(mx + b, 0.f);
      }
    }
    // next loop iteration's barrier (after xs load) guards p1 reuse
  }

  // ---- fc1: h1 = relu(p2 @ FW^T + FB), k chunked by 64 through LDS ----
  const int ti = tid >> 6;   // img pair: 2ti, 2ti+1
  const int to = tid & 63;   // outs: to, to+64
  float* Wch = scratch;      // [128][68] aliases conv scratch
  float a00 = 0.f, a01 = 0.f, a10 = 0.f, a11 = 0.f;
  for (int kc = 0; kc < 400; kc += 64) {
    __syncthreads();  // Wch free (conv done / prev chunk's reads done)
    for (int i = tid; i < 2048; i += 256) {      // 128 outs x 16 float4
      int o = i >> 4, k4 = i & 15;
      int kk = kc + k4 * 4;
      float4 v = {0.f, 0.f, 0.f, 0.f};
      if (kk < 400) v = *(const float4*)(FW + (size_t)o * 400 + kk);
      *(float4*)(Wch + o * 68 + k4 * 4) = v;
    }
    __syncthreads();
    const float* pr0 = &p2L[2 * ti][kc];
    const float* pr1 = &p2L[2 * ti + 1][kc];
    const float* wr0 = Wch + to * 68;
    const float* wr1 = Wch + (to + 64) * 68;
#pragma unroll
    for (int k4 = 0; k4 < 16; ++k4) {
      float4 a0 = *(const float4*)(pr0 + k4 * 4);
      float4 a1 = *(const float4*)(pr1 + k4 * 4);
      float4 w0 = *(const float4*)(wr0 + k4 * 4);
      float4 w1 = *(const float4*)(wr1 + k4 * 4);
      a00 += a0.x * w0.x + a0.y * w0.y + a0.z * w0.z + a0.w * w0.w;
      a01 += a0.x * w1.x + a0.y * w1.y + a0.z * w1.z + a0.w * w1.w;
      a10 += a1.x * w0.x + a1.y * w0.y + a1.z * w0.z + a1.w * w0.w;
      a11 += a1.x * w1.x + a1.y * w1.y + a1.z * w1.z + a1.w * w1.w;
    }
  }
  h1s[2 * ti][to]          = fmaxf(a00 + FB[to], 0.f);
  h1s[2 * ti][to + 64]     = fmaxf(a01 + FB[to + 64], 0.f);
  h1s[2 * ti + 1][to]      = fmaxf(a10 + FB[to], 0.f);
  h1s[2 * ti + 1][to + 64] = fmaxf(a11 + FB[to + 64], 0.f);
  __syncthreads();  // h1s complete; Wch reads done

  // ---- fc2 (no relu) ----
  float* w2s = scratch;           // [64][132]
  float* w3s = scratch + 8448;    // [10][68]
  for (int i = tid; i < 2048; i += 256) {        // 64 outs x 32 float4
    int o = i >> 5, k4 = i & 31;
    *(float4*)(w2s + o * 132 + k4 * 4) = ((const float4*)(F2W + (size_t)o * 128))[k4];
  }
  for (int i = tid; i < 160; i += 256) {         // 10 outs x 16 float4
    int o = i / 16, k4 = i & 15;
    *(float4*)(w3s + o * 68 + k4 * 4) = ((const float4*)(F3W + (size_t)o * 64))[k4];
  }
  __syncthreads();
  {
    const int ti2 = tid & 7;     // img
    const int to2 = tid >> 3;    // outs: to2, to2+32
    float c0 = 0.f, c1 = 0.f;
    const float* hr = &h1s[ti2][0];
    const float* w0r = w2s + to2 * 132;
    const float* w1r = w2s + (to2 + 32) * 132;
#pragma unroll
    for (int k4 = 0; k4 < 32; ++k4) {
      float4 a = *(const float4*)(hr + k4 * 4);
      float4 w0 = *(const float4*)(w0r + k4 * 4);
      float4 w1 = *(const float4*)(w1r + k4 * 4);
      c0 += a.x * w0.x + a.y * w0.y + a.z * w0.z + a.w * w0.w;
      c1 += a.x * w1.x + a.y * w1.y + a.z * w1.z + a.w * w1.w;
    }
    h2s[ti2][to2]      = c0 + F2B[to2];
    h2s[ti2][to2 + 32] = c1 + F2B[to2 + 32];
  }
  __syncthreads();

  // ---- fc3 (no relu) ----
  if (tid < 80) {
    int im = tid / 10, o = tid - im * 10;
    float s = F3B[o];
    const float* hr = &h2s[im][0];
    const float* wr = w3s + o * 68;
#pragma unroll
    for (int k4 = 0; k4 < 16; ++k4) {
      float4 a = *(const float4*)(hr + k4 * 4);
      float4 w = *(const float4*)(wr + k4 * 4);
      s += a.x * w.x + a.y * w.y + a.z * w.z + a.w * w.w;
    }
    OUT[(size_t)(m8 + im) * 10 + o] = s;
  }
}

extern "C" void kernel_launch(void* const* d_in, const int* in_sizes, int n_in,
                              void* d_out, int out_size, void* d_ws, size_t ws_size,
                              hipStream_t stream) {
  const float* x   = (const float*)d_in[0];
  const float* c1w = (const float*)d_in[1];
  const float* c1b = (const float*)d_in[2];
  const float* c2w = (const float*)d_in[3];
  const float* c2b = (const float*)d_in[4];
  const float* fw  = (const float*)d_in[5];
  const float* fb  = (const float*)d_in[6];
  const float* f2w = (const float*)d_in[7];
  const float* f2b = (const float*)d_in[8];
  const float* f3w = (const float*)d_in[9];
  const float* f3b = (const float*)d_in[10];
  float* out = (float*)d_out;

  const int B = in_sizes[0] / 784;   // 16384
  lenet_fused<<<B / 8, 256, 0, stream>>>(x, c1w, c1b, c2w, c2b,
                                         fw, fb, f2w, f2b, f3w, f3b, out);
}

// Round 4
// 153.576 us; speedup vs baseline: 2.0480x; 2.0480x over previous
//
#include <hip/hip_runtime.h>
#include <hip/hip_bf16.h>

typedef _Float16 half8 __attribute__((ext_vector_type(8)));
typedef float floatx4 __attribute__((ext_vector_type(4)));

// Fully-fused LeNet fwd, f16 MFMA for conv2/fc1/fc2. 32 img / 512-thread block.
// LDS ~62.5KB -> 2 blocks/CU. No d_ws usage.
__global__ __launch_bounds__(512, 4) void lenet_mfma(
    const float* __restrict__ X,
    const float* __restrict__ W1, const float* __restrict__ B1,
    const float* __restrict__ W2, const float* __restrict__ B2,
    const float* __restrict__ FW, const float* __restrict__ FB,
    const float* __restrict__ F2W, const float* __restrict__ F2B,
    const float* __restrict__ F3W, const float* __restrict__ F3B,
    float* __restrict__ OUT) {
  // ---- LDS ----
  __shared__ __align__(16) _Float16 p2h[32 * 416];   // pool2 f16 [32][416], cols 400.. zero; h1[32][136] aliases
  __shared__ __align__(16) char p1region[10816];     // p1 f16[4][13][13][8] | h2 f32[32][68]
  __shared__ __align__(16) char region[20480];       // xs f32[4][784] | c2out f16[484][16] | fwdb f16[2][128][40] | w2s f16[64][136]+w3s f32[10][68]
  __shared__ __align__(16) _Float16 w2L[16 * 104];   // conv2 W as [oc][k=tap*8+ic], zero-padded
  __shared__ float w1L[72];
  __shared__ float bc1L[8], bc2L[16], fbL[128], f2bL[64], f3bL[16];
  __shared__ __align__(16) _Float16 zero16[8];

  float* xs = (float*)region;
  _Float16* c2f = (_Float16*)region;
  _Float16* fwdb = (_Float16*)region;
  _Float16* w2sf = (_Float16*)region;
  float* w3sf = (float*)(region + 17408);
  _Float16* p1f = (_Float16*)p1region;
  float* h2f = (float*)p1region;
  _Float16* h1f = p2h;

  const int tid = threadIdx.x;
  const int wave = tid >> 6;
  const int lane = tid & 63;
  const int l15 = lane & 15;
  const int l4 = lane >> 4;
  const int m32 = blockIdx.x * 32;

  // ---- one-time staging ----
  for (int i = tid; i < 72; i += 512) w1L[i] = W1[i];
  if (tid < 8) bc1L[tid] = B1[tid];
  if (tid >= 8 && tid < 24) bc2L[tid - 8] = B2[tid - 8];
  if (tid >= 32 && tid < 160) fbL[tid - 32] = FB[tid - 32];
  if (tid >= 160 && tid < 224) f2bL[tid - 160] = F2B[tid - 160];
  if (tid >= 224 && tid < 234) f3bL[tid - 224] = F3B[tid - 224];
  if (tid >= 240 && tid < 248) zero16[tid - 240] = (_Float16)0.f;
  for (int i = tid; i < 16 * 104; i += 512) {
    int oc = i / 104, k = i % 104;
    _Float16 v = (_Float16)0.f;
    if (k < 72) { int tap = k >> 3, ic = k & 7; v = (_Float16)W2[(oc * 8 + ic) * 9 + tap]; }
    w2L[i] = v;
  }
  if (tid < 512) { int rr = tid >> 4, cc = tid & 15; p2h[rr * 416 + 400 + cc] = (_Float16)0.f; }
  for (int i = tid; i < 784; i += 512) {            // xs for sb=0
    int m = i / 196, f = i % 196;
    ((float4*)(xs + m * 784))[f] = ((const float4*)(X + (size_t)(m32 + m) * 784))[f];
  }
  __syncthreads();

  // conv2 B-fragments: resident in VGPRs for whole kernel
  half8 bw0 = *(const half8*)(w2L + l15 * 104 + 0 + l4 * 8);
  half8 bw1 = *(const half8*)(w2L + l15 * 104 + 32 + l4 * 8);
  half8 bw2 = *(const half8*)(w2L + l15 * 104 + 64 + l4 * 8);
  // per-lane tap offsets for conv2 A-gen (k-tile kt -> tap = kt*4 + l4)
  int off0, off1, off2; int va0, va1, va2;
  {
    int tap, du, dv;
    tap = 0 * 4 + l4; du = (tap >= 6) ? 2 : ((tap >= 3) ? 1 : 0); dv = tap - 3 * du;
    off0 = (du * 13 + dv) * 16; va0 = (tap < 9);
    tap = 1 * 4 + l4; du = (tap >= 6) ? 2 : ((tap >= 3) ? 1 : 0); dv = tap - 3 * du;
    off1 = (du * 13 + dv) * 16; va1 = (tap < 9);
    tap = 2 * 4 + l4; du = (tap >= 6) ? 2 : ((tap >= 3) ? 1 : 0); dv = tap - 3 * du;
    off2 = (du * 13 + dv) * 16; va2 = (tap < 9);
  }

  // ---- conv stages: 8 sub-batches of 4 images ----
  for (int sb = 0; sb < 8; ++sb) {
    // conv1 + relu + pool (fp32 VALU) -> p1f[img][r][c][ch] f16
    for (int t = tid; t < 416; t += 512) {
      int ch = t & 7, rm = t >> 3, m = rm / 13, r = rm % 13;
      float wk[9];
#pragma unroll
      for (int k = 0; k < 9; k++) wk[k] = w1L[ch * 9 + k];
      float b = bc1L[ch];
      const float* Xb = xs + m * 784 + 2 * r * 28;
      float2 A0[4], A1[4];
#pragma unroll
      for (int row = 0; row < 4; row++) {
        A0[row] = *(const float2*)(Xb + row * 28);
        A1[row] = *(const float2*)(Xb + row * 28 + 2);
      }
#pragma unroll
      for (int c = 0; c < 13; c++) {
        if (c) {
#pragma unroll
          for (int row = 0; row < 4; row++) {
            A0[row] = A1[row];
            A1[row] = *(const float2*)(Xb + row * 28 + 2 * c + 2);
          }
        }
        float s0 = 0.f, s1 = 0.f, s2 = 0.f, s3 = 0.f;
#pragma unroll
        for (int u = 0; u < 3; u++) {
          float w0 = wk[u * 3], w1 = wk[u * 3 + 1], w2v = wk[u * 3 + 2];
          float xu0 = A0[u].x, xu1 = A0[u].y, xu2 = A1[u].x, xu3 = A1[u].y;
          s0 += w0 * xu0 + w1 * xu1 + w2v * xu2;
          s1 += w0 * xu1 + w1 * xu2 + w2v * xu3;
          float xd0 = A0[u + 1].x, xd1 = A0[u + 1].y, xd2 = A1[u + 1].x, xd3 = A1[u + 1].y;
          s2 += w0 * xd0 + w1 * xd1 + w2v * xd2;
          s3 += w0 * xd1 + w1 * xd2 + w2v * xd3;
        }
        float mx = fmaxf(fmaxf(s0, s1), fmaxf(s2, s3));
        p1f[((m * 13 + r) * 13 + c) * 8 + ch] = (_Float16)fmaxf(mx + b, 0.f);
      }
    }
    __syncthreads();

    // conv2 via MFMA: M = 4*121 = 484 positions, K = 96 (taps*8ic, zero-pad), N = 16
    for (int mt = wave; mt < 31; mt += 8) {
      int p = mt * 16 + l15; if (p > 483) p = 483;
      int img = p / 121, rem = p - img * 121;
      int r = rem / 11, c = rem - r * 11;
      int base = ((img * 13 + r) * 13 + c) * 16;   // bytes
      const char* p1c = (const char*)p1f;
      floatx4 acc = {0.f, 0.f, 0.f, 0.f};
      half8 a0 = *(const half8*)(va0 ? (p1c + base + off0) : (const char*)zero16);
      acc = __builtin_amdgcn_mfma_f32_16x16x32_f16(a0, bw0, acc, 0, 0, 0);
      half8 a1 = *(const half8*)(va1 ? (p1c + base + off1) : (const char*)zero16);
      acc = __builtin_amdgcn_mfma_f32_16x16x32_f16(a1, bw1, acc, 0, 0, 0);
      half8 a2 = *(const half8*)(va2 ? (p1c + base + off2) : (const char*)zero16);
      acc = __builtin_amdgcn_mfma_f32_16x16x32_f16(a2, bw2, acc, 0, 0, 0);
      int pb = mt * 16 + l4 * 4;
#pragma unroll
      for (int rr = 0; rr < 4; rr++) {
        int pos = pb + rr;
        if (pos < 484) c2f[pos * 16 + l15] = (_Float16)acc[rr];
      }
    }
    __syncthreads();

    // pool2 + bias + relu -> p2h
    for (int t = tid; t < 1600; t += 512) {
      int oc = t & 15, q = t >> 4;
      int m = q / 25, rc = q % 25, r = rc / 5, cc = rc % 5;
      int p00 = m * 121 + (2 * r) * 11 + 2 * cc;
      float v00 = (float)c2f[p00 * 16 + oc];
      float v01 = (float)c2f[(p00 + 1) * 16 + oc];
      float v10 = (float)c2f[(p00 + 11) * 16 + oc];
      float v11 = (float)c2f[(p00 + 12) * 16 + oc];
      float mx = fmaxf(fmaxf(v00, v01), fmaxf(v10, v11));
      p2h[(sb * 4 + m) * 416 + oc * 25 + r * 5 + cc] = (_Float16)fmaxf(mx + bc2L[oc], 0.f);
    }
    __syncthreads();
    if (sb < 7) {
      for (int i = tid; i < 784; i += 512) {
        int m = i / 196, f = i % 196;
        ((float4*)(xs + m * 784))[f] =
            ((const float4*)(X + (size_t)(m32 + (sb + 1) * 4 + m) * 784))[f];
      }
    }
    __syncthreads();
  }

  // ---- fc1: [32 x 416] x [416 x 128] via MFMA, FW double-buffered in LDS ----
  const int so = tid >> 2, sq = tid & 3;
  auto stageFW = [&](int c, int buf) {
    int kk = c * 32 + sq * 8;
    float4 z = {0.f, 0.f, 0.f, 0.f};
    float4 v0 = (kk < 400) ? *(const float4*)(FW + (size_t)so * 400 + kk) : z;
    float4 v1 = (kk + 4 < 400) ? *(const float4*)(FW + (size_t)so * 400 + kk + 4) : z;
    half8 h = {(_Float16)v0.x, (_Float16)v0.y, (_Float16)v0.z, (_Float16)v0.w,
               (_Float16)v1.x, (_Float16)v1.y, (_Float16)v1.z, (_Float16)v1.w};
    *(half8*)(fwdb + buf * 5120 + so * 40 + sq * 8) = h;
  };
  stageFW(0, 0);
  const int mt1 = wave & 1, nt0 = wave >> 1;   // 2 M-tiles x (4+4) N-tiles
  floatx4 acc0 = {0.f, 0.f, 0.f, 0.f}, acc1 = {0.f, 0.f, 0.f, 0.f};
  for (int c = 0; c < 13; ++c) {
    __syncthreads();
    if (c < 12) stageFW(c + 1, (c + 1) & 1);
    const _Float16* fb = fwdb + (c & 1) * 5120;
    half8 a = *(const half8*)(p2h + (mt1 * 16 + l15) * 416 + c * 32 + l4 * 8);
    half8 b0 = *(const half8*)(fb + (nt0 * 16 + l15) * 40 + l4 * 8);
    half8 b1 = *(const half8*)(fb + ((nt0 + 4) * 16 + l15) * 40 + l4 * 8);
    acc0 = __builtin_amdgcn_mfma_f32_16x16x32_f16(a, b0, acc0, 0, 0, 0);
    acc1 = __builtin_amdgcn_mfma_f32_16x16x32_f16(a, b1, acc1, 0, 0, 0);
  }
  __syncthreads();  // all p2 reads done; region free

  // fc1 epilogue -> h1 (aliases p2h), stage fc2/fc3 weights
  {
    float bias0 = fbL[nt0 * 16 + l15], bias1 = fbL[(nt0 + 4) * 16 + l15];
#pragma unroll
    for (int rr = 0; rr < 4; rr++) {
      int img = mt1 * 16 + l4 * 4 + rr;
      h1f[img * 136 + nt0 * 16 + l15] = (_Float16)fmaxf(acc0[rr] + bias0, 0.f);
      h1f[img * 136 + (nt0 + 4) * 16 + l15] = (_Float16)fmaxf(acc1[rr] + bias1, 0.f);
    }
  }
  {
    int o = tid >> 3, q = tid & 7;
    const float* src = F2W + (size_t)o * 128 + q * 16;
    float4 v0 = *(const float4*)(src);
    float4 v1 = *(const float4*)(src + 4);
    float4 v2 = *(const float4*)(src + 8);
    float4 v3 = *(const float4*)(src + 12);
    half8 hA = {(_Float16)v0.x, (_Float16)v0.y, (_Float16)v0.z, (_Float16)v0.w,
                (_Float16)v1.x, (_Float16)v1.y, (_Float16)v1.z, (_Float16)v1.w};
    half8 hB = {(_Float16)v2.x, (_Float16)v2.y, (_Float16)v2.z, (_Float16)v2.w,
                (_Float16)v3.x, (_Float16)v3.y, (_Float16)v3.z, (_Float16)v3.w};
    *(half8*)(w2sf + o * 136 + q * 16) = hA;
    *(half8*)(w2sf + o * 136 + q * 16 + 8) = hB;
  }
  for (int i = tid; i < 640; i += 512) w3sf[(i >> 6) * 68 + (i & 63)] = F3W[i];
  __syncthreads();

  // ---- fc2: [32 x 128] x [128 x 64] MFMA (no relu) -> h2 f32 ----
  {
    floatx4 acc2 = {0.f, 0.f, 0.f, 0.f};
#pragma unroll
    for (int kt = 0; kt < 4; kt++) {
      half8 a = *(const half8*)(h1f + (mt1 * 16 + l15) * 136 + kt * 32 + l4 * 8);
      half8 b = *(const half8*)(w2sf + (nt0 * 16 + l15) * 136 + kt * 32 + l4 * 8);
      acc2 = __builtin_amdgcn_mfma_f32_16x16x32_f16(a, b, acc2, 0, 0, 0);
    }
    float b2v = f2bL[nt0 * 16 + l15];
#pragma unroll
    for (int rr = 0; rr < 4; rr++) {
      int img = mt1 * 16 + l4 * 4 + rr;
      h2f[img * 68 + nt0 * 16 + l15] = acc2[rr] + b2v;
    }
  }
  __syncthreads();

  // ---- fc3: 32x10, K=64, fp32 VALU ----
  {
    int img = tid >> 4, o = tid & 15;
    if (o < 10) {
      float s = f3bL[o];
#pragma unroll
      for (int k4 = 0; k4 < 16; k4++) {
        float4 hv = *(const float4*)(h2f + img * 68 + k4 * 4);
        float4 wv = *(const float4*)(w3sf + o * 68 + k4 * 4);
        s += hv.x * wv.x + hv.y * wv.y + hv.z * wv.z + hv.w * wv.w;
      }
      OUT[(size_t)(m32 + img) * 10 + o] = s;
    }
  }
}

extern "C" void kernel_launch(void* const* d_in, const int* in_sizes, int n_in,
                              void* d_out, int out_size, void* d_ws, size_t ws_size,
                              hipStream_t stream) {
  const float* x   = (const float*)d_in[0];
  const float* c1w = (const float*)d_in[1];
  const float* c1b = (const float*)d_in[2];
  const float* c2w = (const float*)d_in[3];
  const float* c2b = (const float*)d_in[4];
  const float* fw  = (const float*)d_in[5];
  const float* fb  = (const float*)d_in[6];
  const float* f2w = (const float*)d_in[7];
  const float* f2b = (const float*)d_in[8];
  const float* f3w = (const float*)d_in[9];
  const float* f3b = (const float*)d_in[10];
  float* out = (float*)d_out;

  const int B = in_sizes[0] / 784;   // 16384
  lenet_mfma<<<B / 32, 512, 0, stream>>>(x, c1w, c1b, c2w, c2b,
                                         fw, fb, f2w, f2b, f3w, f3b, out);
}

// Round 5
// 136.157 us; speedup vs baseline: 2.3100x; 1.1279x over previous
//
#include <hip/hip_runtime.h>
#include <hip/hip_bf16.h>

typedef _Float16 half8 __attribute__((ext_vector_type(8)));
typedef float floatx4 __attribute__((ext_vector_type(4)));

// LeNet fwd, all-MFMA convs with window-ordered M (pool in-register).
// 16 img / 512-thread block, 1024 blocks, LDS ~39.4KB -> 4 blocks/CU.
__global__ __launch_bounds__(512, 8) void lenet_mfma2(
    const float* __restrict__ X,
    const float* __restrict__ W1, const float* __restrict__ B1,
    const float* __restrict__ W2, const float* __restrict__ B2,
    const float* __restrict__ FW, const float* __restrict__ FB,
    const float* __restrict__ F2W, const float* __restrict__ F2B,
    const float* __restrict__ F3W, const float* __restrict__ F3B,
    float* __restrict__ OUT) {
  __shared__ __align__(16) _Float16 p2h[16 * 424];  // pool2 [16][424], 400..423 zero; h1f/h2f alias
  __shared__ __align__(16) char region[18944];      // conv: xs f16[4][28][32] + p1f f16[4][169][8] | fc: w2sf[64][136] + w3sf f16[10][72]
  __shared__ __align__(16) _Float16 w2L[16 * 104];  // conv2 B [oc][k=tap*8+ic] zero-pad
  __shared__ __align__(16) _Float16 c1B[1280];      // conv1 B 2x[16][40] (k<16 real, rest 0)
  __shared__ float bc1L[8], bc2L[16], fbL[128], f2bL[64], f3bL[16];
  __shared__ __align__(16) _Float16 zero16[8];

  _Float16* xs = (_Float16*)region;                 // [4][28][32]
  _Float16* p1f = (_Float16*)(region + 7168);       // [4][169][8]
  _Float16* w2sf = (_Float16*)region;               // [64][136]
  _Float16* w3sf = (_Float16*)(region + 17408);     // [10][72]
  _Float16* h1f = p2h;                              // [16][136]
  float* h2f = (float*)((char*)p2h + 6656);         // [16][68]

  const int tid = threadIdx.x;
  const int wave = tid >> 6, lane = tid & 63, l15 = lane & 15, l4 = lane >> 4;
  const int m16 = blockIdx.x * 16;
  const float4* X4 = (const float4*)X;

  // ---- one-time staging ----
  if (tid < 8) bc1L[tid] = B1[tid];
  else if (tid < 24) bc2L[tid - 8] = B2[tid - 8];
  else if (tid < 152) fbL[tid - 24] = FB[tid - 24];
  else if (tid < 216) f2bL[tid - 152] = F2B[tid - 152];
  else if (tid < 226) f3bL[tid - 216] = F3B[tid - 216];
  else if (tid >= 240 && tid < 248) zero16[tid - 240] = (_Float16)0.f;

  for (int i = tid; i < 1664; i += 512) {           // conv2 B
    int oc = i / 104, k = i % 104;
    _Float16 v = (_Float16)0.f;
    if (k < 72) { int tap = k >> 3, ic = k & 7; v = (_Float16)W2[(oc * 8 + ic) * 9 + tap]; }
    w2L[i] = v;
  }
  for (int i = tid; i < 1280; i += 512) {           // conv1 B (2 mats)
    int mat = i / 640, r = i % 640, n = r / 40, k = r % 40;
    float v = 0.f;
    if (k < 16) {
      int q = mat * 2 + (n >> 3), ch = n & 7;
      int uu = (k >> 2) - (q >> 1), vv = (k & 3) - (q & 1);
      if (uu >= 0 && uu < 3 && vv >= 0 && vv < 3) v = W1[ch * 9 + uu * 3 + vv];
    }
    c1B[i] = (_Float16)v;
  }
  if (tid < 384) { int rr = tid / 24; p2h[rr * 424 + 400 + tid % 24] = (_Float16)0.f; }
  for (int i = tid; i < 784; i += 512) {            // xs for sb=0 (f32 -> f16)
    int img = i / 196, f = i % 196, row = f / 7, fc = f % 7;
    float4 v = X4[(size_t)(m16 + img) * 196 + f];
    union { _Float16 h[4]; uint2 u; } pk;
    pk.h[0] = (_Float16)v.x; pk.h[1] = (_Float16)v.y;
    pk.h[2] = (_Float16)v.z; pk.h[3] = (_Float16)v.w;
    *(uint2*)(xs + (img * 28 + row) * 32 + fc * 4) = pk.u;
  }
  __syncthreads();

  // resident B-fragments
  const half8 cb0 = *(const half8*)(c1B + l15 * 40 + l4 * 8);
  const half8 cb1 = *(const half8*)(c1B + 640 + l15 * 40 + l4 * 8);
  const half8 bw0 = *(const half8*)(w2L + l15 * 104 + 0 + l4 * 8);
  const half8 bw1 = *(const half8*)(w2L + l15 * 104 + 32 + l4 * 8);
  const half8 bw2 = *(const half8*)(w2L + l15 * 104 + 64 + l4 * 8);
  int off0, off1, off2, va0, va1, va2;              // conv2 tap offsets
  {
    int tap, du, dv;
    tap = 0 * 4 + l4; du = (tap >= 6) ? 2 : ((tap >= 3) ? 1 : 0); dv = tap - 3 * du;
    off0 = (du * 13 + dv) * 16; va0 = (tap < 9);
    tap = 1 * 4 + l4; du = (tap >= 6) ? 2 : ((tap >= 3) ? 1 : 0); dv = tap - 3 * du;
    off1 = (du * 13 + dv) * 16; va1 = (tap < 9);
    tap = 2 * 4 + l4; du = (tap >= 6) ? 2 : ((tap >= 3) ? 1 : 0); dv = tap - 3 * du;
    off2 = (du * 13 + dv) * 16; va2 = (tap < 9);
  }

  // ---- conv stages: 4 sub-batches of 4 images ----
  for (int sb = 0; sb < 4; ++sb) {
    // conv1+pool via MFMA: M = 676 windows (43 tiles), K=32 (4x4 patch), N=16=(qsel,ch)
    for (int mt = wave; mt < 43; mt += 8) {
      int m = mt * 16 + l15; if (m > 675) m = 675;
      int img = m / 169, rem = m - img * 169, wr = rem / 13, wc = rem - wr * 13;
      int rowa = img * 28 + 2 * wr + 2 * l4; if (rowa > 110) rowa = 110;
      const uint32_t* xd = (const uint32_t*)xs;
      int dw = rowa * 16 + wc;
      union { uint32_t u[4]; half8 h; } ua;
      ua.u[0] = xd[dw]; ua.u[1] = xd[dw + 1];
      ua.u[2] = xd[dw + 16]; ua.u[3] = xd[dw + 17];
      floatx4 ac1 = {0.f, 0.f, 0.f, 0.f}, ac2 = {0.f, 0.f, 0.f, 0.f};
      ac1 = __builtin_amdgcn_mfma_f32_16x16x32_f16(ua.h, cb0, ac1, 0, 0, 0);
      ac2 = __builtin_amdgcn_mfma_f32_16x16x32_f16(ua.h, cb1, ac2, 0, 0, 0);
#pragma unroll
      for (int rr = 0; rr < 4; ++rr) {
        float mx = fmaxf(ac1[rr], ac2[rr]);          // q={qsel, qsel+2}
        mx = fmaxf(mx, __shfl_xor(mx, 8));           // combine qsel pair
        int w = mt * 16 + 4 * l4 + rr;
        if (l15 < 8 && w < 676) {
          int wi = w / 169, wrem = w - wi * 169, pr = wrem / 13, pcc = wrem - pr * 13;
          p1f[(wi * 169 + pr * 13 + pcc) * 8 + l15] = (_Float16)fmaxf(mx + bc1L[l15], 0.f);
        }
      }
    }
    __syncthreads();
    // conv2+pool via MFMA: M = 400 = 100 windows x 4 quadrants (25 tiles), K=96, N=16 oc
    for (int mt = wave; mt < 25; mt += 8) {
      int w = mt * 4 + (l15 >> 2), q = l15 & 3;
      int img = w / 25, rem = w - img * 25, wr = rem / 5, wc = rem - wr * 5;
      int r = 2 * wr + (q >> 1), c = 2 * wc + (q & 1);
      const char* pbase = (const char*)p1f;
      int base = (img * 169 + r * 13 + c) * 16;
      floatx4 acc = {0.f, 0.f, 0.f, 0.f};
      half8 a0 = *(const half8*)(va0 ? pbase + base + off0 : (const char*)zero16);
      acc = __builtin_amdgcn_mfma_f32_16x16x32_f16(a0, bw0, acc, 0, 0, 0);
      half8 a1 = *(const half8*)(va1 ? pbase + base + off1 : (const char*)zero16);
      acc = __builtin_amdgcn_mfma_f32_16x16x32_f16(a1, bw1, acc, 0, 0, 0);
      half8 a2 = *(const half8*)(va2 ? pbase + base + off2 : (const char*)zero16);
      acc = __builtin_amdgcn_mfma_f32_16x16x32_f16(a2, bw2, acc, 0, 0, 0);
      float mx = fmaxf(fmaxf(acc[0], acc[1]), fmaxf(acc[2], acc[3]));  // lane's 4 rows = pool window
      int w2 = mt * 4 + l4, i2 = w2 / 25, rm2 = w2 - i2 * 25, wr2 = rm2 / 5, wc2 = rm2 - wr2 * 5;
      p2h[(sb * 4 + i2) * 424 + l15 * 25 + wr2 * 5 + wc2] = (_Float16)fmaxf(mx + bc2L[l15], 0.f);
    }
    if (sb < 3) {                                    // prefetch next xs during conv2 phase
      for (int i = tid; i < 784; i += 512) {
        int img = i / 196, f = i % 196, row = f / 7, fc = f % 7;
        float4 v = X4[(size_t)(m16 + (sb + 1) * 4 + img) * 196 + f];
        union { _Float16 h[4]; uint2 u; } pk;
        pk.h[0] = (_Float16)v.x; pk.h[1] = (_Float16)v.y;
        pk.h[2] = (_Float16)v.z; pk.h[3] = (_Float16)v.w;
        *(uint2*)(xs + (img * 28 + row) * 32 + fc * 4) = pk.u;
      }
    }
    __syncthreads();
  }

  // ---- stage fc2/fc3 weights (region free now) ----
  {
    int o = tid >> 3, qq = tid & 7;
    const float* src = F2W + (size_t)o * 128 + qq * 16;
    float4 v0 = *(const float4*)(src);
    float4 v1 = *(const float4*)(src + 4);
    float4 v2 = *(const float4*)(src + 8);
    float4 v3 = *(const float4*)(src + 12);
    half8 hA = {(_Float16)v0.x, (_Float16)v0.y, (_Float16)v0.z, (_Float16)v0.w,
                (_Float16)v1.x, (_Float16)v1.y, (_Float16)v1.z, (_Float16)v1.w};
    half8 hB = {(_Float16)v2.x, (_Float16)v2.y, (_Float16)v2.z, (_Float16)v2.w,
                (_Float16)v3.x, (_Float16)v3.y, (_Float16)v3.z, (_Float16)v3.w};
    *(half8*)(w2sf + o * 136 + qq * 16) = hA;
    *(half8*)(w2sf + o * 136 + qq * 16 + 8) = hB;
  }
  if (tid < 80) {
    int o = tid / 8, qq = tid & 7;
    const float* src = F3W + o * 64 + qq * 8;
    float4 v0 = *(const float4*)(src);
    float4 v1 = *(const float4*)(src + 4);
    half8 h = {(_Float16)v0.x, (_Float16)v0.y, (_Float16)v0.z, (_Float16)v0.w,
               (_Float16)v1.x, (_Float16)v1.y, (_Float16)v1.z, (_Float16)v1.w};
    *(half8*)(w3sf + o * 72 + qq * 8) = h;
  }

  // ---- fc1: [16 x 416] x [416 x 128], B direct from global (L2), reg dbuf ----
  const int o1 = wave * 16 + l15;
  const float4* FWq = (const float4*)FW;
  const float4 fz = {0.f, 0.f, 0.f, 0.f};
  float4 cur0, cur1, nxt0, nxt1;
  { int kn = l4 * 8;
    cur0 = FWq[(size_t)o1 * 100 + (kn >> 2)];
    cur1 = FWq[(size_t)o1 * 100 + (kn >> 2) + 1]; }
  floatx4 fa = {0.f, 0.f, 0.f, 0.f};
  for (int c = 0; c < 13; ++c) {
    if (c < 12) {
      int kn = (c + 1) * 32 + l4 * 8;
      nxt0 = (kn < 400) ? FWq[(size_t)o1 * 100 + (kn >> 2)] : fz;
      nxt1 = (kn + 4 < 400) ? FWq[(size_t)o1 * 100 + (kn >> 2) + 1] : fz;
    }
    half8 a = *(const half8*)(p2h + l15 * 424 + c * 32 + l4 * 8);
    half8 b = {(_Float16)cur0.x, (_Float16)cur0.y, (_Float16)cur0.z, (_Float16)cur0.w,
               (_Float16)cur1.x, (_Float16)cur1.y, (_Float16)cur1.z, (_Float16)cur1.w};
    fa = __builtin_amdgcn_mfma_f32_16x16x32_f16(a, b, fa, 0, 0, 0);
    cur0 = nxt0; cur1 = nxt1;
  }
  __syncthreads();  // p2h reads done (h1f aliases)
  {
    float bia = fbL[o1];
#pragma unroll
    for (int rr = 0; rr < 4; ++rr)
      h1f[(4 * l4 + rr) * 136 + o1] = (_Float16)fmaxf(fa[rr] + bia, 0.f);
  }
  __syncthreads();

  // ---- fc2: [16 x 128] x [128 x 64] on waves 0..3 ----
  if (wave < 4) {
    floatx4 a2 = {0.f, 0.f, 0.f, 0.f};
#pragma unroll
    for (int kt = 0; kt < 4; ++kt) {
      half8 a = *(const half8*)(h1f + l15 * 136 + kt * 32 + l4 * 8);
      half8 b = *(const half8*)(w2sf + (wave * 16 + l15) * 136 + kt * 32 + l4 * 8);
      a2 = __builtin_amdgcn_mfma_f32_16x16x32_f16(a, b, a2, 0, 0, 0);
    }
    float bb = f2bL[wave * 16 + l15];
#pragma unroll
    for (int rr = 0; rr < 4; ++rr)
      h2f[(4 * l4 + rr) * 68 + wave * 16 + l15] = a2[rr] + bb;
  }
  __syncthreads();

  // ---- fc3: 16 x 10, K=64 ----
  if (tid < 160) {
    int img = tid / 10, o = tid - img * 10;
    float s = f3bL[o];
#pragma unroll
    for (int kc = 0; kc < 8; ++kc) {
      half8 wv = *(const half8*)(w3sf + o * 72 + kc * 8);
      float4 hA = *(const float4*)(h2f + img * 68 + kc * 8);
      float4 hB = *(const float4*)(h2f + img * 68 + kc * 8 + 4);
      s += hA.x * (float)wv[0] + hA.y * (float)wv[1] + hA.z * (float)wv[2] + hA.w * (float)wv[3]
         + hB.x * (float)wv[4] + hB.y * (float)wv[5] + hB.z * (float)wv[6] + hB.w * (float)wv[7];
    }
    OUT[(size_t)(m16 + img) * 10 + o] = s;
  }
}

extern "C" void kernel_launch(void* const* d_in, const int* in_sizes, int n_in,
                              void* d_out, int out_size, void* d_ws, size_t ws_size,
                              hipStream_t stream) {
  const float* x   = (const float*)d_in[0];
  const float* c1w = (const float*)d_in[1];
  const float* c1b = (const float*)d_in[2];
  const float* c2w = (const float*)d_in[3];
  const float* c2b = (const float*)d_in[4];
  const float* fw  = (const float*)d_in[5];
  const float* fb  = (const float*)d_in[6];
  const float* f2w = (const float*)d_in[7];
  const float* f2b = (const float*)d_in[8];
  const float* f3w = (const float*)d_in[9];
  const float* f3b = (const float*)d_in[10];
  float* out = (float*)d_out;

  const int B = in_sizes[0] / 784;   // 16384
  lenet_mfma2<<<B / 16, 512, 0, stream>>>(x, c1w, c1b, c2w, c2b,
                                          fw, fb, f2w, f2b, f3w, f3b, out);
}

// Round 7
// 132.238 us; speedup vs baseline: 2.3784x; 1.0296x over previous
//
#include <hip/hip_runtime.h>
#include <hip/hip_bf16.h>

typedef _Float16 half8 __attribute__((ext_vector_type(8)));
typedef float floatx4 __attribute__((ext_vector_type(4)));

// LeNet fwd, all-MFMA convs with window-ordered M (pool in-register).
// 16 img / 512-thread block, 1024 blocks, LDS ~40.2KB -> 4 blocks/CU.
__global__ __launch_bounds__(512, 8) void lenet_mfma3(
    const float* __restrict__ X,
    const float* __restrict__ W1, const float* __restrict__ B1,
    const float* __restrict__ W2, const float* __restrict__ B2,
    const float* __restrict__ FW, const float* __restrict__ FB,
    const float* __restrict__ F2W, const float* __restrict__ F2B,
    const float* __restrict__ F3W, const float* __restrict__ F3B,
    float* __restrict__ OUT) {
  __shared__ __align__(16) _Float16 p2h[16 * 424];  // pool2 [16][424], 400..423 zero; h1f/h2f alias
  __shared__ __align__(16) char region[19776];      // conv: xs f16[4][28][40] + p1f f16[4*169][8] | fc: w2sf[64][136] + w3sf f16[10][72]
  __shared__ __align__(16) _Float16 w2L[16 * 104];  // conv2 B [oc][k=tap*8+ic] zero-pad
  __shared__ __align__(16) _Float16 c1B[1280];      // conv1 B 2x[16][40] (k<16 real, rest 0)
  __shared__ float bc1L[8], bc2L[16], fbL[128], f2bL[64], f3bL[16];

  _Float16* xs = (_Float16*)region;                 // [4][28][40] (row pad: bank-shift)
  _Float16* p1f = (_Float16*)(region + 8960);       // [4*169][8] window-linear
  _Float16* w2sf = (_Float16*)region;               // [64][136]
  _Float16* w3sf = (_Float16*)(region + 17408);     // [10][72]
  _Float16* h1f = p2h;                              // [16][136]
  float* h2f = (float*)((char*)p2h + 6656);         // [16][68]

  const int tid = threadIdx.x;
  const int wave = tid >> 6, lane = tid & 63, l15 = lane & 15, l4 = lane >> 4;
  const int m16 = blockIdx.x * 16;
  const float4* X4 = (const float4*)X;

  // ---- one-time staging ----
  if (tid < 8) bc1L[tid] = B1[tid];
  else if (tid < 24) bc2L[tid - 8] = B2[tid - 8];
  else if (tid < 152) fbL[tid - 24] = FB[tid - 24];
  else if (tid < 216) f2bL[tid - 152] = F2B[tid - 152];
  else if (tid < 226) f3bL[tid - 216] = F3B[tid - 216];

  for (int i = tid; i < 1664; i += 512) {           // conv2 B
    int oc = i / 104, k = i % 104;
    _Float16 v = (_Float16)0.f;
    if (k < 72) { int tap = k >> 3, ic = k & 7; v = (_Float16)W2[(oc * 8 + ic) * 9 + tap]; }
    w2L[i] = v;
  }
  for (int i = tid; i < 1280; i += 512) {           // conv1 B (2 mats)
    int mat = i / 640, r = i % 640, n = r / 40, k = r % 40;
    float v = 0.f;
    if (k < 16) {
      int q = mat * 2 + (n >> 3), ch = n & 7;
      int uu = (k >> 2) - (q >> 1), vv = (k & 3) - (q & 1);
      if (uu >= 0 && uu < 3 && vv >= 0 && vv < 3) v = W1[ch * 9 + uu * 3 + vv];
    }
    c1B[i] = (_Float16)v;
  }
  if (tid < 384) { int rr = tid / 24; p2h[rr * 424 + 400 + tid % 24] = (_Float16)0.f; }
  for (int i = tid; i < 784; i += 512) {            // xs for sb=0 (f32 -> f16)
    int img = i / 196, f = i % 196, row = f / 7, fc = f % 7;
    float4 v = X4[(size_t)(m16 + img) * 196 + f];
    union { _Float16 h[4]; uint2 u; } pk;
    pk.h[0] = (_Float16)v.x; pk.h[1] = (_Float16)v.y;
    pk.h[2] = (_Float16)v.z; pk.h[3] = (_Float16)v.w;
    *(uint2*)(xs + (img * 28 + row) * 40 + fc * 4) = pk.u;
  }
  __syncthreads();

  // resident B-fragments + per-lane constants
  const half8 cb0 = *(const half8*)(c1B + l15 * 40 + l4 * 8);
  const half8 cb1 = *(const half8*)(c1B + 640 + l15 * 40 + l4 * 8);
  const half8 bw0 = *(const half8*)(w2L + l15 * 104 + 0 + l4 * 8);
  const half8 bw1 = *(const half8*)(w2L + l15 * 104 + 32 + l4 * 8);
  const half8 bw2 = *(const half8*)(w2L + l15 * 104 + 64 + l4 * 8);
  const float b1v = bc1L[l15 & 7];
  const float b2v = bc2L[l15];
  int off0, off1, off2;                             // conv2 tap byte-offsets (invalid taps: in-bounds garbage x zero-B)
  {
    int tap, du, dv;
    tap = 0 * 4 + l4; du = (tap >= 6) ? 2 : ((tap >= 3) ? 1 : 0); dv = tap - 3 * du;
    off0 = (du * 13 + dv) * 16;
    tap = 1 * 4 + l4; du = (tap >= 6) ? 2 : ((tap >= 3) ? 1 : 0); dv = tap - 3 * du;
    off1 = (du * 13 + dv) * 16;
    tap = 2 * 4 + l4; du = (tap >= 6) ? 2 : ((tap >= 3) ? 1 : 0); dv = tap - 3 * du;
    off2 = (du * 13 + dv) * 16;
  }

  // ---- conv stages: 4 sub-batches of 4 images ----
  for (int sb = 0; sb < 4; ++sb) {
    // conv1+pool via MFMA: M = 676 windows (43 tiles), K=32 (4x4 patch), N=16=(qsel,ch)
    for (int mt = wave; mt < 43; mt += 8) {
      int m = mt * 16 + l15; if (m > 675) m = 675;
      int img = m / 169, rem = m - img * 169, wr = rem / 13, wc = rem - wr * 13;
      int rowa = img * 28 + 2 * wr + 2 * l4; if (rowa > 110) rowa = 110;
      const uint32_t* xd = (const uint32_t*)xs;
      int dw = rowa * 20 + wc;
      union { uint32_t u[4]; half8 h; } ua;
      ua.u[0] = xd[dw]; ua.u[1] = xd[dw + 1];
      ua.u[2] = xd[dw + 20]; ua.u[3] = xd[dw + 21];
      floatx4 ac1 = {0.f, 0.f, 0.f, 0.f}, ac2 = {0.f, 0.f, 0.f, 0.f};
      ac1 = __builtin_amdgcn_mfma_f32_16x16x32_f16(ua.h, cb0, ac1, 0, 0, 0);
      ac2 = __builtin_amdgcn_mfma_f32_16x16x32_f16(ua.h, cb1, ac2, 0, 0, 0);
      const int w0 = mt * 16 + 4 * l4;
#pragma unroll
      for (int rr = 0; rr < 4; ++rr) {
        float mx = fmaxf(ac1[rr], ac2[rr]);          // q={qsel, qsel+2}
        mx = fmaxf(mx, __shfl_xor(mx, 8));           // combine qsel pair
        if (l15 < 8 && w0 + rr < 676)
          p1f[(w0 + rr) * 8 + l15] = (_Float16)fmaxf(mx + b1v, 0.f);
      }
    }
    __syncthreads();
    // conv2+pool via MFMA: M = 400 = 100 windows x 4 quadrants (25 tiles), K=96, N=16 oc
    for (int mt = wave; mt < 25; mt += 8) {
      int w = mt * 4 + (l15 >> 2), q = l15 & 3;
      int img = w / 25, rem = w - img * 25, wr = rem / 5, wc = rem - wr * 5;
      int r = 2 * wr + (q >> 1), c = 2 * wc + (q & 1);
      const char* pbase = (const char*)p1f;
      int base = (img * 169 + r * 13 + c) * 16;
      floatx4 acc = {0.f, 0.f, 0.f, 0.f};
      half8 a0 = *(const half8*)(pbase + base + off0);
      acc = __builtin_amdgcn_mfma_f32_16x16x32_f16(a0, bw0, acc, 0, 0, 0);
      half8 a1 = *(const half8*)(pbase + base + off1);
      acc = __builtin_amdgcn_mfma_f32_16x16x32_f16(a1, bw1, acc, 0, 0, 0);
      half8 a2 = *(const half8*)(pbase + base + off2);
      acc = __builtin_amdgcn_mfma_f32_16x16x32_f16(a2, bw2, acc, 0, 0, 0);
      float mx = fmaxf(fmaxf(acc[0], acc[1]), fmaxf(acc[2], acc[3]));  // lane's 4 rows = pool window
      int w2 = mt * 4 + l4, i2 = w2 / 25, rm2 = w2 - i2 * 25;
      p2h[(sb * 4 + i2) * 424 + l15 * 25 + rm2] = (_Float16)fmaxf(mx + b2v, 0.f);
    }
    if (sb < 3) {                                    // prefetch next xs during conv2 phase
      for (int i = tid; i < 784; i += 512) {
        int img = i / 196, f = i % 196, row = f / 7, fc = f % 7;
        float4 v = X4[(size_t)(m16 + (sb + 1) * 4 + img) * 196 + f];
        union { _Float16 h[4]; uint2 u; } pk;
        pk.h[0] = (_Float16)v.x; pk.h[1] = (_Float16)v.y;
        pk.h[2] = (_Float16)v.z; pk.h[3] = (_Float16)v.w;
        *(uint2*)(xs + (img * 28 + row) * 40 + fc * 4) = pk.u;
      }
    }
    __syncthreads();
  }

  // ---- stage fc2/fc3 weights (region free now) ----
  {
    int o = tid >> 3, qq = tid & 7;
    const float* src = F2W + (size_t)o * 128 + qq * 16;
    float4 v0 = *(const float4*)(src);
    float4 v1 = *(const float4*)(src + 4);
    float4 v2 = *(const float4*)(src + 8);
    float4 v3 = *(const float4*)(src + 12);
    half8 hA = {(_Float16)v0.x, (_Float16)v0.y, (_Float16)v0.z, (_Float16)v0.w,
                (_Float16)v1.x, (_Float16)v1.y, (_Float16)v1.z, (_Float16)v1.w};
    half8 hB = {(_Float16)v2.x, (_Float16)v2.y, (_Float16)v2.z, (_Float16)v2.w,
                (_Float16)v3.x, (_Float16)v3.y, (_Float16)v3.z, (_Float16)v3.w};
    *(half8*)(w2sf + o * 136 + qq * 16) = hA;
    *(half8*)(w2sf + o * 136 + qq * 16 + 8) = hB;
  }
  if (tid < 80) {
    int o = tid / 8, qq = tid & 7;
    const float* src = F3W + o * 64 + qq * 8;
    float4 v0 = *(const float4*)(src);
    float4 v1 = *(const float4*)(src + 4);
    half8 h = {(_Float16)v0.x, (_Float16)v0.y, (_Float16)v0.z, (_Float16)v0.w,
               (_Float16)v1.x, (_Float16)v1.y, (_Float16)v1.z, (_Float16)v1.w};
    *(half8*)(w3sf + o * 72 + qq * 8) = h;
  }

  // ---- fc1: [16 x 416] x [416 x 128], B direct from global (L2), reg dbuf ----
  const int o1 = wave * 16 + l15;
  const float4* FWq = (const float4*)FW;
  const float4 fz = {0.f, 0.f, 0.f, 0.f};
  float4 cur0, cur1, nxt0, nxt1;
  { int kn = l4 * 8;
    cur0 = FWq[(size_t)o1 * 100 + (kn >> 2)];
    cur1 = FWq[(size_t)o1 * 100 + (kn >> 2) + 1]; }
  floatx4 fa = {0.f, 0.f, 0.f, 0.f};
  for (int c = 0; c < 13; ++c) {
    if (c < 12) {
      int kn = (c + 1) * 32 + l4 * 8;
      nxt0 = (kn < 400) ? FWq[(size_t)o1 * 100 + (kn >> 2)] : fz;
      nxt1 = (kn + 4 < 400) ? FWq[(size_t)o1 * 100 + (kn >> 2) + 1] : fz;
    }
    half8 a = *(const half8*)(p2h + l15 * 424 + c * 32 + l4 * 8);
    half8 b = {(_Float16)cur0.x, (_Float16)cur0.y, (_Float16)cur0.z, (_Float16)cur0.w,
               (_Float16)cur1.x, (_Float16)cur1.y, (_Float16)cur1.z, (_Float16)cur1.w};
    fa = __builtin_amdgcn_mfma_f32_16x16x32_f16(a, b, fa, 0, 0, 0);
    cur0 = nxt0; cur1 = nxt1;
  }
  __syncthreads();  // p2h reads done (h1f aliases)
  {
    float bia = fbL[o1];
#pragma unroll
    for (int rr = 0; rr < 4; ++rr)
      h1f[(4 * l4 + rr) * 136 + o1] = (_Float16)fmaxf(fa[rr] + bia, 0.f);
  }
  __syncthreads();

  // ---- fc2: [16 x 128] x [128 x 64] on waves 0..3 ----
  if (wave < 4) {
    floatx4 a2 = {0.f, 0.f, 0.f, 0.f};
#pragma unroll
    for (int kt = 0; kt < 4; ++kt) {
      half8 a = *(const half8*)(h1f + l15 * 136 + kt * 32 + l4 * 8);
      half8 b = *(const half8*)(w2sf + (wave * 16 + l15) * 136 + kt * 32 + l4 * 8);
      a2 = __builtin_amdgcn_mfma_f32_16x16x32_f16(a, b, a2, 0, 0, 0);
    }
    float bb = f2bL[wave * 16 + l15];
#pragma unroll
    for (int rr = 0; rr < 4; ++rr)
      h2f[(4 * l4 + rr) * 68 + wave * 16 + l15] = a2[rr] + bb;
  }
  __syncthreads();

  // ---- fc3: 16 x 10, K=64 ----
  if (tid < 160) {
    int img = tid / 10, o = tid - img * 10;
    float s = f3bL[o];
#pragma unroll
    for (int kc = 0; kc < 8; ++kc) {
      half8 wv = *(const half8*)(w3sf + o * 72 + kc * 8);
      float4 hA = *(const float4*)(h2f + img * 68 + kc * 8);
      float4 hB = *(const float4*)(h2f + img * 68 + kc * 8 + 4);
      s += hA.x * (float)wv[0] + hA.y * (float)wv[1] + hA.z * (float)wv[2] + hA.w * (float)wv[3]
         + hB.x * (float)wv[4] + hB.y * (float)wv[5] + hB.z * (float)wv[6] + hB.w * (float)wv[7];
    }
    OUT[(size_t)(m16 + img) * 10 + o] = s;
  }
}

extern "C" void kernel_launch(void* const* d_in, const int* in_sizes, int n_in,
                              void* d_out, int out_size, void* d_ws, size_t ws_size,
                              hipStream_t stream) {
  const float* x   = (const float*)d_in[0];
  const float* c1w = (const float*)d_in[1];
  const float* c1b = (const float*)d_in[2];
  const float* c2w = (const float*)d_in[3];
  const float* c2b = (const float*)d_in[4];
  const float* fw  = (const float*)d_in[5];
  const float* fb  = (const float*)d_in[6];
  const float* f2w = (const float*)d_in[7];
  const float* f2b = (const float*)d_in[8];
  const float* f3w = (const float*)d_in[9];
  const float* f3b = (const float*)d_in[10];
  float* out = (float*)d_out;

  const int B = in_sizes[0] / 784;   // 16384
  lenet_mfma3<<<B / 16, 512, 0, stream>>>(x, c1w, c1b, c2w, c2b,
                                          fw, fb, f2w, f2b, f3w, f3b, out);
}